// Round 1
// baseline (82.584 us; speedup 1.0000x reference)
//
#include <hip/hip_runtime.h>

#define NB    32
#define NPB   16384
#define CHUNK 2048
#define K     2048
#define NF    64

// Monotone map: float -> uint32 such that float order == unsigned order.
__device__ __forceinline__ unsigned mono(float f) {
  unsigned u = __float_as_uint(f);
  return (u & 0x80000000u) ? ~u : (u | 0x80000000u);
}

// Sort each 2048-element chunk of the key column descending by
// key64 = (mono(value) << 32) | ~index   (ties -> lower index first).
__global__ __launch_bounds__(256) void chunk_sort_kernel(const float* __restrict__ in,
                                                         unsigned long long* __restrict__ keys_out) {
  __shared__ unsigned long long s[CHUNK];
  const int b = blockIdx.x >> 3;   // batch
  const int c = blockIdx.x & 7;    // chunk within batch
  const int base = c * CHUNK;
  const float* bin = in + (size_t)b * NPB * NF;

  for (int j = threadIdx.x; j < CHUNK; j += 256) {
    int gi = base + j;
    float v = bin[(size_t)gi * NF];          // feature 0 of row gi
    s[j] = ((unsigned long long)mono(v) << 32) | (unsigned)(~(unsigned)gi);
  }
  __syncthreads();

  // Bitonic sort, descending overall.
  for (int size = 2; size <= CHUNK; size <<= 1) {
    for (int stride = size >> 1; stride >= 1; stride >>= 1) {
      for (int t = threadIdx.x; t < CHUNK / 2; t += 256) {
        int pos = 2 * t - (t & (stride - 1));
        unsigned long long a = s[pos], bb = s[pos + stride];
        bool desc = ((pos & size) == 0);
        bool sw = desc ? (a < bb) : (a > bb);
        if (sw) { s[pos] = bb; s[pos + stride] = a; }
      }
      __syncthreads();
    }
  }

  unsigned long long* out = keys_out + (size_t)b * NPB + base;
  for (int j = threadIdx.x; j < CHUNK; j += 256) out[j] = s[j];
}

// Per batch: merge 8 sorted-descending chunks down to the sorted top-2048,
// using bitonic top-k merges entirely in LDS (128 KiB).
__global__ __launch_bounds__(1024) void merge_kernel(const unsigned long long* __restrict__ keys_in,
                                                     int* __restrict__ idx_out) {
  __shared__ unsigned long long s[NPB];   // 128 KiB
  const int b = blockIdx.x;
  const unsigned long long* kin = keys_in + (size_t)b * NPB;
  for (int j = threadIdx.x; j < NPB; j += 1024) s[j] = kin[j];
  __syncthreads();

  for (int gap = CHUNK; gap < NPB; gap <<= 1) {     // 2048, 4096, 8192
    const int nm = NPB / (2 * gap);                 // 4, 2, 1 merges
    // Half-cleaner: A[i] = max(A[i], B[K-1-i]) keeps top-K multiset, result bitonic.
    for (int t = threadIdx.x; t < nm * K; t += 1024) {
      int m = t >> 11;              // t / K
      int i = t & (K - 1);
      unsigned long long* A = s + (size_t)m * 2 * gap;
      unsigned long long a = A[i];
      unsigned long long bb = A[gap + (K - 1 - i)];
      A[i] = a > bb ? a : bb;
    }
    __syncthreads();
    // Bitonic merge (descending) of each bitonic A of length K.
    for (int stride = K / 2; stride >= 1; stride >>= 1) {
      for (int t = threadIdx.x; t < nm * (K / 2); t += 1024) {
        int m = t >> 10;            // t / (K/2)
        int p = t & (K / 2 - 1);
        unsigned long long* A = s + (size_t)m * 2 * gap;
        int pos = 2 * p - (p & (stride - 1));
        unsigned long long a = A[pos], bb = A[pos + stride];
        if (a < bb) { A[pos] = bb; A[pos + stride] = a; }
      }
      __syncthreads();
    }
  }

  int* iout = idx_out + (size_t)b * K;
  for (int j = threadIdx.x; j < K; j += 1024) {
    unsigned low = (unsigned)(s[j] & 0xFFFFFFFFull);
    iout[j] = (int)(~low);          // recover row index
  }
}

// Gather the selected rows: one float4 per thread, coalesced 256 B rows.
__global__ __launch_bounds__(256) void gather_kernel(const float* __restrict__ in,
                                                     const int* __restrict__ idx,
                                                     float* __restrict__ out) {
  int tid = blockIdx.x * 256 + threadIdx.x;
  int f4  = tid & 15;               // which float4 of the row
  int row = tid >> 4;               // global output row in [0, 32*2048)
  int b   = row >> 11;
  int i   = row & (K - 1);
  int gi  = idx[(size_t)b * K + i];
  const float4* src = reinterpret_cast<const float4*>(in + ((size_t)b * NPB + gi) * NF) + f4;
  float4*       dst = reinterpret_cast<float4*>(out + (size_t)row * NF) + f4;
  *dst = *src;
}

extern "C" void kernel_launch(void* const* d_in, const int* in_sizes, int n_in,
                              void* d_out, int out_size, void* d_ws, size_t ws_size,
                              hipStream_t stream) {
  const float* in = (const float*)d_in[0];
  float* out = (float*)d_out;

  // Scratch: sorted chunk keys (4 MiB) live in the front of d_out (16 MiB,
  // fully rewritten by gather afterwards); indices (256 KiB) live in d_ws.
  unsigned long long* keys = (unsigned long long*)d_out;
  int* idx = (int*)d_ws;

  chunk_sort_kernel<<<NB * 8, 256, 0, stream>>>(in, keys);
  merge_kernel<<<NB, 1024, 0, stream>>>(keys, idx);
  gather_kernel<<<(NB * K * NF / 4) / 256, 256, 0, stream>>>(in, idx, out);
}

// Round 2
// 69.829 us; speedup vs baseline: 1.1827x; 1.1827x over previous
//
#include <hip/hip_runtime.h>

#define NB    32
#define NPB   16384
#define CHUNK 2048
#define K     2048
#define NF    64

// Monotone map: float -> uint32 such that float order == unsigned order.
__device__ __forceinline__ unsigned mono(float f) {
  unsigned u = __float_as_uint(f);
  return (u & 0x80000000u) ? ~u : (u | 0x80000000u);
}

// Sort each 2048-element chunk of the key column descending by
// key64 = (mono(value) << 32) | ~index   (ties -> lower index first).
__global__ __launch_bounds__(512) void chunk_sort_kernel(const float* __restrict__ in,
                                                         unsigned long long* __restrict__ keys_out) {
  __shared__ unsigned long long s[CHUNK];
  const int b = blockIdx.x >> 3;   // batch
  const int c = blockIdx.x & 7;    // chunk within batch
  const int base = c * CHUNK;
  const float* bin = in + (size_t)b * NPB * NF;

  for (int j = threadIdx.x; j < CHUNK; j += 512) {
    int gi = base + j;
    float v = bin[(size_t)gi * NF];          // feature 0 of row gi
    s[j] = ((unsigned long long)mono(v) << 32) | (unsigned)(~(unsigned)gi);
  }
  __syncthreads();

  // Bitonic sort, descending overall. 66 barriered stages, 2 CE/thread/stage.
  for (int size = 2; size <= CHUNK; size <<= 1) {
    for (int stride = size >> 1; stride >= 1; stride >>= 1) {
      for (int t = threadIdx.x; t < CHUNK / 2; t += 512) {
        int pos = 2 * t - (t & (stride - 1));
        unsigned long long a = s[pos], bb = s[pos + stride];
        bool desc = ((pos & size) == 0);
        if (desc ? (a < bb) : (a > bb)) { s[pos] = bb; s[pos + stride] = a; }
      }
      __syncthreads();
    }
  }

  unsigned long long* out = keys_out + (size_t)b * NPB + base;
  for (int j = threadIdx.x; j < CHUNK; j += 512) out[j] = s[j];
}

// One merge level: each block takes a pair of sorted-descending K-lists
// (A at offset 0, B at offset `gap` within the pair region), keeps the
// top-K of the union sorted descending, writes it back to A's location.
// If idx_out != nullptr (final level), writes recovered indices instead.
__global__ __launch_bounds__(512) void merge_level_kernel(unsigned long long* __restrict__ keys,
                                                          int gap, int nm,
                                                          int* __restrict__ idx_out) {
  __shared__ unsigned long long s[K];   // 16 KiB
  const int m = blockIdx.x % nm;
  const int b = blockIdx.x / nm;
  unsigned long long* A = keys + (size_t)b * NPB + (size_t)m * 2 * gap;

  // Half-cleaner: s[i] = max(A[i], B[K-1-i]) keeps exactly the top-K
  // multiset of the union and the result is bitonic.
  for (int i = threadIdx.x; i < K; i += 512) {
    unsigned long long a = A[i];
    unsigned long long bb = A[gap + (K - 1 - i)];
    s[i] = a > bb ? a : bb;
  }
  __syncthreads();

  // Bitonic merge (descending) of the bitonic length-K sequence: 11 stages.
  for (int stride = K / 2; stride >= 1; stride >>= 1) {
    for (int t = threadIdx.x; t < K / 2; t += 512) {
      int pos = 2 * t - (t & (stride - 1));
      unsigned long long a = s[pos], bb = s[pos + stride];
      if (a < bb) { s[pos] = bb; s[pos + stride] = a; }
    }
    __syncthreads();
  }

  if (idx_out == nullptr) {
    for (int i = threadIdx.x; i < K; i += 512) A[i] = s[i];
  } else {
    int* iout = idx_out + (size_t)b * K;
    for (int i = threadIdx.x; i < K; i += 512) {
      unsigned low = (unsigned)(s[i] & 0xFFFFFFFFull);
      iout[i] = (int)(~low);        // recover row index
    }
  }
}

// Gather the selected rows: one float4 per thread, coalesced 256 B rows.
__global__ __launch_bounds__(256) void gather_kernel(const float* __restrict__ in,
                                                     const int* __restrict__ idx,
                                                     float* __restrict__ out) {
  int tid = blockIdx.x * 256 + threadIdx.x;
  int f4  = tid & 15;               // which float4 of the row
  int row = tid >> 4;               // global output row in [0, 32*2048)
  int b   = row >> 11;
  int i   = row & (K - 1);
  int gi  = idx[(size_t)b * K + i];
  const float4* src = reinterpret_cast<const float4*>(in + ((size_t)b * NPB + gi) * NF) + f4;
  float4*       dst = reinterpret_cast<float4*>(out + (size_t)row * NF) + f4;
  *dst = *src;
}

extern "C" void kernel_launch(void* const* d_in, const int* in_sizes, int n_in,
                              void* d_out, int out_size, void* d_ws, size_t ws_size,
                              hipStream_t stream) {
  const float* in = (const float*)d_in[0];
  float* out = (float*)d_out;

  // Scratch: sorted chunk keys (4 MiB) live in the front of d_out (16 MiB,
  // fully rewritten by gather afterwards); indices (256 KiB) live in d_ws.
  unsigned long long* keys = (unsigned long long*)d_out;
  int* idx = (int*)d_ws;

  chunk_sort_kernel<<<NB * 8, 512, 0, stream>>>(in, keys);
  // Tournament of truncating merges: 8 -> 4 -> 2 -> 1 lists per batch.
  merge_level_kernel<<<NB * 4, 512, 0, stream>>>(keys, 2048, 4, nullptr);
  merge_level_kernel<<<NB * 2, 512, 0, stream>>>(keys, 4096, 2, nullptr);
  merge_level_kernel<<<NB * 1, 512, 0, stream>>>(keys, 8192, 1, idx);
  gather_kernel<<<(NB * K * NF / 4) / 256, 256, 0, stream>>>(in, idx, out);
}

// Round 3
// 64.444 us; speedup vs baseline: 1.2815x; 1.0835x over previous
//
#include <hip/hip_runtime.h>

#define NB    32
#define NPB   16384
#define K     2048
#define NF    64
#define NTHR  1024
#define NW    16      // waves per select block

// Monotone map: float -> uint32 such that float order == unsigned order.
__device__ __forceinline__ unsigned mono(float f) {
  unsigned u = __float_as_uint(f);
  return (u & 0x80000000u) ? ~u : (u | 0x80000000u);
}

// Dense key column: keybuf[b*NPB+i] = mono(in[b,i,0]). Full-grid, HBM-bound.
__global__ __launch_bounds__(256) void extract_keys_kernel(const float* __restrict__ in,
                                                           unsigned* __restrict__ keybuf) {
  int i = blockIdx.x * 256 + threadIdx.x;          // global row in [0, NB*NPB)
  keybuf[i] = mono(in[(size_t)i * NF]);
}

// Per batch (one block): exact radix-select of the rank-K key64, compact the
// K winners, bitonic-sort them descending, write indices.
// key64(i) = (mono << 32) | ~i  -> desc by value, ties asc by index (== lax.top_k).
__global__ __launch_bounds__(NTHR) void select_sort_kernel(const unsigned* __restrict__ keybuf,
                                                           int* __restrict__ idx_out) {
  __shared__ unsigned km[NPB];                 // 64 KiB
  __shared__ unsigned whist[NW][256];          // 16 KiB
  __shared__ unsigned sfx[257];
  __shared__ unsigned long long wkeys[K];      // 16 KiB
  __shared__ unsigned wbase[NW];
  __shared__ unsigned sh_D, sh_rem;
  __shared__ unsigned long long sh_prefix;

  const int b    = blockIdx.x;
  const int tid  = threadIdx.x;
  const int wid  = tid >> 6;
  const int lane = tid & 63;

  for (int i = tid; i < NPB; i += NTHR) km[i] = keybuf[(size_t)b * NPB + i];
  if (tid == 0) { sh_rem = K; sh_prefix = 0; }
  __syncthreads();

  // 8 MSB-first radix rounds over key64.
  for (int r = 0; r < 8; ++r) {
    const int shift = 56 - 8 * r;
    for (int i = tid; i < NW * 256; i += NTHR) ((unsigned*)whist)[i] = 0;
    __syncthreads();
    const unsigned long long prefix = sh_prefix;
    const unsigned rem = sh_rem;
    for (int i = tid; i < NPB; i += NTHR) {
      unsigned long long key = ((unsigned long long)km[i] << 32) | (unsigned)~(unsigned)i;
      bool inclass = (r == 0) || ((key >> (shift + 8)) == prefix);
      if (inclass) atomicAdd(&whist[wid][(unsigned)(key >> shift) & 255u], 1u);
    }
    __syncthreads();
    // Wave 0: merge the NW histograms and suffix-scan 256 buckets.
    if (wid == 0) {
      unsigned h0 = 0, h1 = 0, h2 = 0, h3 = 0;
      for (int w = 0; w < NW; ++w) {
        h0 += whist[w][4 * lane + 0];
        h1 += whist[w][4 * lane + 1];
        h2 += whist[w][4 * lane + 2];
        h3 += whist[w][4 * lane + 3];
      }
      unsigned s = h0 + h1 + h2 + h3;
      unsigned p = s;                             // inclusive suffix over lanes
      for (int off = 1; off < 64; off <<= 1) {
        unsigned t = __shfl_down(p, off);
        if (lane + off < 64) p += t;
      }
      unsigned run = p - s;                       // sum over lanes > this one
      unsigned s3 = run + h3, s2 = s3 + h2, s1 = s2 + h1, s0 = s1 + h0;
      sfx[4 * lane + 0] = s0; sfx[4 * lane + 1] = s1;
      sfx[4 * lane + 2] = s2; sfx[4 * lane + 3] = s3;
      if (lane == 0) sfx[256] = 0;
    }
    __syncthreads();
    if (tid < 256) {
      unsigned above = sfx[tid + 1];
      if (sfx[tid] >= rem && above < rem) {       // exactly one bucket satisfies
        sh_D = (unsigned)tid;
        sh_rem = rem - above;
      }
    }
    __syncthreads();
    if (tid == 0) sh_prefix = (sh_prefix << 8) | sh_D;
    __syncthreads();
  }
  const unsigned long long T = sh_prefix;         // exact rank-K (2048th-largest) key64

  // Compact winners (key64 >= T -> exactly K of them) via shuffle prefix sums.
  unsigned nw = 0;
  for (int i = tid; i < NPB; i += NTHR) {
    unsigned long long key = ((unsigned long long)km[i] << 32) | (unsigned)~(unsigned)i;
    nw += (key >= T);
  }
  unsigned p = nw;
  for (int off = 1; off < 64; off <<= 1) {
    unsigned t = __shfl_up(p, off);
    if (lane >= off) p += t;
  }
  unsigned excl = p - nw;
  if (lane == 63) wbase[wid] = p;                 // wave total
  __syncthreads();
  if (tid == 0) {
    unsigned acc = 0;
    for (int w = 0; w < NW; ++w) { unsigned t = wbase[w]; wbase[w] = acc; acc += t; }
  }
  __syncthreads();
  unsigned pos = wbase[wid] + excl;
  for (int i = tid; i < NPB; i += NTHR) {
    unsigned long long key = ((unsigned long long)km[i] << 32) | (unsigned)~(unsigned)i;
    if (key >= T) wkeys[pos++] = key;
  }
  __syncthreads();

  // Bitonic sort of the K winners, descending. 1 CE/thread/stage.
  for (int size = 2; size <= K; size <<= 1) {
    for (int stride = size >> 1; stride >= 1; stride >>= 1) {
      int pos2 = 2 * tid - (tid & (stride - 1));
      bool desc = ((pos2 & size) == 0);
      unsigned long long a = wkeys[pos2], bb = wkeys[pos2 + stride];
      if (desc ? (a < bb) : (a > bb)) { wkeys[pos2] = bb; wkeys[pos2 + stride] = a; }
      __syncthreads();
    }
  }

  int* iout = idx_out + (size_t)b * K;
  for (int i = tid; i < K; i += NTHR)
    iout[i] = (int)(~(unsigned)(wkeys[i] & 0xFFFFFFFFull));
}

// Gather the selected rows: one float4 per thread, coalesced 256 B rows.
__global__ __launch_bounds__(256) void gather_kernel(const float* __restrict__ in,
                                                     const int* __restrict__ idx,
                                                     float* __restrict__ out) {
  int tid = blockIdx.x * 256 + threadIdx.x;
  int f4  = tid & 15;               // which float4 of the row
  int row = tid >> 4;               // global output row in [0, NB*K)
  int b   = row >> 11;
  int i   = row & (K - 1);
  int gi  = idx[(size_t)b * K + i];
  const float4* src = reinterpret_cast<const float4*>(in + ((size_t)b * NPB + gi) * NF) + f4;
  float4*       dst = reinterpret_cast<float4*>(out + (size_t)row * NF) + f4;
  *dst = *src;
}

extern "C" void kernel_launch(void* const* d_in, const int* in_sizes, int n_in,
                              void* d_out, int out_size, void* d_ws, size_t ws_size,
                              hipStream_t stream) {
  const float* in = (const float*)d_in[0];
  float* out = (float*)d_out;

  // d_ws layout: [0, 2 MiB) dense keys; [2 MiB, 2.25 MiB) indices.
  unsigned* keybuf = (unsigned*)d_ws;
  int* idx = (int*)((char*)d_ws + (size_t)NB * NPB * sizeof(unsigned));

  extract_keys_kernel<<<(NB * NPB) / 256, 256, 0, stream>>>(in, keybuf);
  select_sort_kernel<<<NB, NTHR, 0, stream>>>(keybuf, idx);
  gather_kernel<<<(NB * K * NF / 4) / 256, 256, 0, stream>>>(in, idx, out);
}